// Round 6
// baseline (418.567 us; speedup 1.0000x reference)
//
#include <hip/hip_runtime.h>

// EncodecEuclideanCodebook — R9.
//   x: [131072, 128] fp32, embed: [1024, 128] fp32.
//   out: quantize [131072*128] f32, then embed_ind [131072] (indices as f32).
//
// score = 2*x.e - ||e||^2 (argmax-equivalent). Approx: K=128 fp16 MFMA GEMM
// fp16(x) . fp16(e), MARGIN 0.10 (~22 sigma). Flagged rows (~1%) re-scored
// exactly in fp32 by refine_kernel. Gather fused into vq/refine epilogues.
//
// R8b post-mortem: counted-vmcnt pipeline worked (130->89us). Now VALUBusy 61%
// dominates (MfmaUtil 15, HBM 15): ~4K VALU instr/thread vs ~1.2K useful ->
// per-block fixed machinery (conversion, preload, 16x stage addr + barriers,
// top-2 chains, merge, gather addr) replicated 2048x. R9:
//  (a) 128 rows/block, 1024 thr, 16 waves, grid 1024: same per-wave tile
//      (bh[4][2], acc[4][2], ~60 VGPR), halves E-streams/barriers/stage addr;
//      1 glds16/wave/stage -> vmcnt(1). 2 blocks/CU = 32 waves = 100% occ;
//      waves_per_eu(8) caps VGPR at 64 (fits: measured 60 live).
//  (b) epilogue: sc = fma(2,acc,-e2); sec' = v_med3(sc,best,sec) (exact
//      second-max); best/bidx via max+cndmask. 5 VALU/score, no branches.
//      Ties -> margin 0 -> flagged -> refine gives reference tie-break.

#define N_ROWS (64 * 2048)
#define DIM 128
#define BINS 1024
#define MARGIN 0.10f

typedef __attribute__((ext_vector_type(8))) _Float16 half8;  // 16 B = 4 VGPR
typedef __attribute__((ext_vector_type(4))) float f32x4;

__device__ __forceinline__ void glds16(const void* g, void* l) {
    __builtin_amdgcn_global_load_lds((const __attribute__((address_space(1))) char*)g,
                                     (__attribute__((address_space(3))) char*)l, 16, 0, 0);
}

// e_img: 16 stages x 16 KB fp16. Stage S = chunk*4 + ks holds bins
// [256*chunk,+256) x k [32*ks,+32); byte off = b*64 + 16*(g2 ^ ((b>>2)&3)).
__global__ __launch_bounds__(256) void prep_kernel(const float* __restrict__ embed,
                                                   _Float16* __restrict__ e_img,
                                                   float* __restrict__ esq_g,
                                                   int* __restrict__ counter) {
    int bin = blockIdx.x * 256 + threadIdx.x;
    if (bin == 0) *counter = 0;
    const float4* e4 = (const float4*)(embed + (size_t)bin * DIM);
    int c = bin >> 8, b = bin & 255;
    float s = 0.f;
#pragma unroll
    for (int g = 0; g < 16; ++g) {
        float4 v0 = e4[2 * g], v1 = e4[2 * g + 1];
        s += v0.x * v0.x + v0.y * v0.y + v0.z * v0.z + v0.w * v0.w;
        s += v1.x * v1.x + v1.y * v1.y + v1.z * v1.z + v1.w * v1.w;
        float f[8] = {v0.x, v0.y, v0.z, v0.w, v1.x, v1.y, v1.z, v1.w};
        half8 H;
#pragma unroll
        for (int j = 0; j < 8; ++j) H[j] = (_Float16)f[j];
        int ks = g >> 2, g2 = g & 3;
        size_t off = ((size_t)(c * 4 + ks) << 14) + (size_t)b * 64 + 16 * (g2 ^ ((b >> 2) & 3));
        *(half8*)((char*)e_img + off) = H;
    }
    esq_g[bin] = s;
}

// 1024 threads = 16 waves. Wave wv: row-group h = wv>>2 (32 rows of 128),
// bin-quarter bq = wv&3 (64 bins of each 256-bin chunk). Wave tile 64x32.
// LDS 52 KB: [0,48K) three 16KB e-stage buffers (buf0+buf1 double as xh
// (32KB) during the prologue), [48K,52K) esq (live whole kernel).
__global__ __launch_bounds__(1024) __attribute__((amdgpu_waves_per_eu(8)))
void vq_mfma_kernel(const float* __restrict__ x,
                    const _Float16* __restrict__ e_img,
                    const float* __restrict__ esq_g,
                    const float* __restrict__ embed,
                    float* __restrict__ out_idx,
                    float* __restrict__ out_q,
                    int* __restrict__ list,
                    int* __restrict__ counter) {
    __shared__ __align__(16) char smem[53248];
    float* esq_s = (float*)(smem + 49152);

    const int t = threadIdx.x;
    const int wv = t >> 6, lane = t & 63, q = lane >> 4, L15 = lane & 15;
    const int h = wv >> 2, bq = wv & 3;
    const int R0 = blockIdx.x * 128;

    // ---- stage esq -> LDS; convert x tile (128 rows) -> fp16 in LDS ----
    {
        esq_s[t] = esq_g[t];
        const float4* xg = (const float4*)(x + (size_t)R0 * DIM);
#pragma unroll
        for (int qq = 0; qq < 2; ++qq) {
            int G = qq * 1024 + t;
            int row = G >> 4, g = G & 15;
            float4 v0 = xg[row * 32 + 2 * g];
            float4 v1 = xg[row * 32 + 2 * g + 1];
            float f[8] = {v0.x, v0.y, v0.z, v0.w, v1.x, v1.y, v1.z, v1.w};
            half8 H;
#pragma unroll
            for (int j = 0; j < 8; ++j) H[j] = (_Float16)f[j];
            int off = row * 256 + 16 * (g ^ (row & 7));
            *(half8*)(smem + off) = H;
        }
    }
    __syncthreads();

    // ---- preload x B-fragments: rows 32h+16nt+L15, k-group (ks<<2)|q ----
    half8 bh[4][2];
    const int rbase = (32 * h + L15) * 256;
#pragma unroll
    for (int ks = 0; ks < 4; ++ks) {
        const int sB = 16 * ((((ks << 2) | q)) ^ (L15 & 7));
#pragma unroll
        for (int nt = 0; nt < 2; ++nt)
            bh[ks][nt] = *(const half8*)(smem + rbase + nt * 4096 + sB);
    }
    __syncthreads();   // xh (buf0+buf1) dead -> e-stage buffers 0,1

    const int aOff = (64 * bq + L15) * 64 + 16 * (q ^ ((L15 >> 2) & 3));

    // ---- prologue prefetch: stages 0,1 -> buf0,buf1 (1 KB per wave each) ----
    {
        const char* src = (const char*)e_img;
        const int off = wv << 10;
#pragma unroll
        for (int st = 0; st < 2; ++st)
            glds16(src + ((size_t)st << 14) + off + lane * 16, smem + st * 16384 + off);
        asm volatile("s_waitcnt vmcnt(1)" ::: "memory");   // stage-0 segment landed
    }
    __builtin_amdgcn_s_barrier();
    asm volatile("" ::: "memory");                         // no reads hoist above barrier

    float best[2], sec[2];
    int bidx[2];
#pragma unroll
    for (int nt = 0; nt < 2; ++nt) { best[nt] = -3.4e38f; sec[nt] = -3.4e38f; bidx[nt] = 0; }

    for (int c = 0; c < 4; ++c) {                 // 4 chunks of 256 bins
        f32x4 acc[4][2];
#pragma unroll
        for (int mt = 0; mt < 4; ++mt)
#pragma unroll
            for (int nt = 0; nt < 2; ++nt) acc[mt][nt] = (f32x4){0.f, 0.f, 0.f, 0.f};

#pragma unroll
        for (int s = 0; s < 4; ++s) {             // 4 k-stages of 32
            const int gs = c * 4 + s;
            // issue prefetch of stage gs+2 first: overlaps this stage's MFMAs.
            // dst buf (gs+2)%3 == (gs-1)%3: readers done at entry barrier.
            if (gs < 14) {
                const char* src = (const char*)e_img + ((size_t)(gs + 2) << 14);
                char* dst = smem + ((gs + 2) % 3) * 16384;
                const int off = wv << 10;
                glds16(src + off + lane * 16, dst + off);
            }
            const char* buf = smem + (gs % 3) * 16384;
            half8 a[4];
#pragma unroll
            for (int mt = 0; mt < 4; ++mt)
                a[mt] = *(const half8*)(buf + aOff + mt * 1024);
#pragma unroll
            for (int mt = 0; mt < 4; ++mt)
#pragma unroll
                for (int nt = 0; nt < 2; ++nt)
                    acc[mt][nt] = __builtin_amdgcn_mfma_f32_16x16x32_f16(a[mt], bh[s][nt], acc[mt][nt], 0, 0, 0);
            // counted wait: keep newest stage's load in flight, guarantee
            // stage gs+1's segment (the oldest outstanding) has landed.
            if (gs < 14) {
                asm volatile("s_waitcnt vmcnt(1)" ::: "memory");
            } else if (gs == 14) {
                asm volatile("s_waitcnt vmcnt(0)" ::: "memory");
            }
            __builtin_amdgcn_s_barrier();
            asm volatile("" ::: "memory");        // pin next stage's ds_reads below
        }

        // ---- chunk epilogue: per-lane top-2 over its 16 bins (ascending) ----
        // sec' = med3(sc, best, sec) is the exact new second-max; best/bidx
        // via strict > (keeps first occurrence). Ties -> margin 0 -> refined.
#pragma unroll
        for (int mt = 0; mt < 4; ++mt)
#pragma unroll
            for (int r = 0; r < 4; ++r) {
                int bin = 256 * c + 64 * bq + 16 * mt + 4 * q + r;
                float e2 = esq_s[bin];
#pragma unroll
                for (int nt = 0; nt < 2; ++nt) {
                    float sc = fmaf(2.f, acc[mt][nt][r], -e2);
                    bool gt = sc > best[nt];
                    sec[nt] = __builtin_amdgcn_fmed3f(sc, best[nt], sec[nt]);
                    best[nt] = gt ? sc : best[nt];
                    bidx[nt] = gt ? bin : bidx[nt];
                }
            }
    }

    // ---- cross-quad top-2 merge (within wave) ----
#pragma unroll
    for (int nt = 0; nt < 2; ++nt) {
        for (int off = 16; off <= 32; off <<= 1) {
            float ob = __shfl_xor(best[nt], off);
            float os = __shfl_xor(sec[nt], off);
            int oi = __shfl_xor(bidx[nt], off);
            if (ob > best[nt]) { sec[nt] = fmaxf(best[nt], os); best[nt] = ob; bidx[nt] = oi; }
            else sec[nt] = fmaxf(sec[nt], ob);
        }
    }
    __syncthreads();                              // full drain; e-bufs dead -> scratch
    float* sv = (float*)smem;                     // [16 waves][32 rows][b,s,i]
    int* fidx = (int*)(smem + 8192);              // [128]
    if (q == 0) {
#pragma unroll
        for (int nt = 0; nt < 2; ++nt) {
            int base = (wv * 32 + 16 * nt + L15) * 3;
            sv[base] = best[nt]; sv[base + 1] = sec[nt];
            ((int*)sv)[base + 2] = bidx[nt];
        }
    }
    __syncthreads();
    if (t < 128) {
        int hh = t >> 5, r32 = t & 31;
        int base0 = ((4 * hh) * 32 + r32) * 3;
        float b0 = sv[base0], s0 = sv[base0 + 1];
        int i0 = ((int*)sv)[base0 + 2];
        for (int w = 1; w < 4; ++w) {
            int base = ((4 * hh + w) * 32 + r32) * 3;
            float ob = sv[base], os = sv[base + 1];
            int oi = ((int*)sv)[base + 2];
            if (ob > b0) { s0 = fmaxf(b0, os); b0 = ob; i0 = oi; }
            else s0 = fmaxf(s0, ob);
        }
        out_idx[R0 + t] = (float)i0;
        fidx[t] = i0;
        if (b0 - s0 < MARGIN) {
            int pos = atomicAdd(counter, 1);
            list[pos] = R0 + t;
        }
    }
    __syncthreads();

    // ---- fused gather: 128 rows x 32 float4 = 4 per thread ----
    {
        const float4* eg = (const float4*)embed;
        float4* og = (float4*)(out_q + (size_t)R0 * DIM);
#pragma unroll
        for (int i = 0; i < 4; ++i) {
            int f = i * 1024 + t;
            int r = f >> 5, cc = f & 31;
            og[(size_t)r * 32 + cc] = eg[(size_t)fidx[r] * 32 + cc];
        }
    }
}

// Compacted exact fp32 refine (16 flagged rows x 1024 bins per tile), with
// fused gather for its rows. First-max tie-break = reference semantics.
#define SWB(r, c4) ((r) * 128 + 4 * ((c4) ^ ((r) & 31)))
__global__ __launch_bounds__(256) void refine_kernel(const float* __restrict__ x,
                                                     const float* __restrict__ embed,
                                                     const float* __restrict__ esq_g,
                                                     float* __restrict__ out_idx,
                                                     float* __restrict__ out_q,
                                                     const int* __restrict__ list,
                                                     const int* __restrict__ counter) {
    __shared__ float xr[16 * 128];    // 8 KB
    __shared__ float bs[64 * 128];    // 32 KB
    __shared__ int rowbuf[16];
    __shared__ int ridx[16];

    const int t = threadIdx.x;
    const int tx = t & 63;
    const int ty = t >> 6;
    const int F = *counter;

    for (int tile = blockIdx.x; tile * 16 < F; tile += gridDim.x) {
        const int base = tile * 16;
        __syncthreads();
        if (t < 16) rowbuf[t] = list[min(base + t, F - 1)];
        __syncthreads();
#pragma unroll
        for (int i = 0; i < 2; ++i) {
            int f = i * 256 + t;
            int r = f >> 5, cc = f & 31;
            float4 v = ((const float4*)(x + (size_t)rowbuf[r] * DIM))[cc];
            *(float4*)&xr[r * 128 + cc * 4] = v;
        }

        float bb[4]; int bi[4];
#pragma unroll
        for (int rr = 0; rr < 4; ++rr) { bb[rr] = -3.4e38f; bi[rr] = 0; }

        for (int chunk = 0; chunk < 16; ++chunk) {
            __syncthreads();
            const float4* eg = (const float4*)(embed + (size_t)chunk * 64 * DIM);
#pragma unroll
            for (int i = 0; i < 8; ++i) {
                int f = i * 256 + t;
                int r = f >> 5, cc = f & 31;
                float4 v = eg[f];
                *(float4*)&bs[SWB(r, cc)] = v;
            }
            __syncthreads();

            float acc[4];
#pragma unroll
            for (int rr = 0; rr < 4; ++rr) acc[rr] = 0.f;
#pragma unroll 8
            for (int k4 = 0; k4 < 32; ++k4) {
                float4 b = *(const float4*)&bs[SWB(tx, k4)];
#pragma unroll
                for (int rr = 0; rr < 4; ++rr) {
                    float4 a = *(const float4*)&xr[(4 * ty + rr) * 128 + k4 * 4];
                    acc[rr] = fmaf(a.x, b.x, acc[rr]);
                    acc[rr] = fmaf(a.y, b.y, acc[rr]);
                    acc[rr] = fmaf(a.z, b.z, acc[rr]);
                    acc[rr] = fmaf(a.w, b.w, acc[rr]);
                }
            }
            const int bin = chunk * 64 + tx;
            const float e2 = esq_g[bin];
#pragma unroll
            for (int rr = 0; rr < 4; ++rr) {
                float sc = 2.f * acc[rr] - e2;
                if (sc > bb[rr]) { bb[rr] = sc; bi[rr] = bin; }
            }
        }

        __syncthreads();
        float* vals = bs;
        int* idxs = (int*)(bs + 1024);
#pragma unroll
        for (int rr = 0; rr < 4; ++rr) {
            vals[(4 * ty + rr) * 64 + tx] = bb[rr];
            idxs[(4 * ty + rr) * 64 + tx] = bi[rr];
        }
        __syncthreads();
        if (t < 16) {
            float bv = vals[t * 64];
            int bix = idxs[t * 64];
            for (int j = 1; j < 64; ++j) {
                float v = vals[t * 64 + j];
                int id = idxs[t * 64 + j];
                if (v > bv || (v == bv && id < bix)) { bv = v; bix = id; }
            }
            ridx[t] = bix;
            if (base + t < F) out_idx[rowbuf[t]] = (float)bix;
        }
        __syncthreads();
        // fused gather for this tile's rows (dup tail rows rewrite same data)
        {
            const float4* eg = (const float4*)embed;
#pragma unroll
            for (int i = 0; i < 2; ++i) {
                int f = i * 256 + t;
                int r = f >> 5, cc = f & 31;
                float4* og = (float4*)(out_q + (size_t)rowbuf[r] * DIM);
                og[cc] = eg[(size_t)ridx[r] * 32 + cc];
            }
        }
    }
}

extern "C" void kernel_launch(void* const* d_in, const int* in_sizes, int n_in,
                              void* d_out, int out_size, void* d_ws, size_t ws_size,
                              hipStream_t stream) {
    const float* x = (const float*)d_in[0];
    const float* embed = (const float*)d_in[1];
    float* out_q = (float*)d_out;
    float* out_idx = out_q + (size_t)N_ROWS * DIM;
    char* wsb = (char*)d_ws;
    _Float16* e_img = (_Float16*)wsb;                         // 256 KB (16 x 16 KB)
    float* esq_g = (float*)(wsb + (16 << 14));                // 4 KB
    int* counter = (int*)(wsb + (16 << 14) + 4096);           // 4 B (+pad)
    int* list = (int*)(wsb + (16 << 14) + 4096 + 128);        // 512 KB

    prep_kernel<<<BINS / 256, 256, 0, stream>>>(embed, e_img, esq_g, counter);
    vq_mfma_kernel<<<N_ROWS / 128, 1024, 0, stream>>>(x, e_img, esq_g, embed,
                                                      out_idx, out_q, list, counter);
    refine_kernel<<<1024, 256, 0, stream>>>(x, embed, esq_g, out_idx, out_q, list, counter);
}

// Round 7
// 261.032 us; speedup vs baseline: 1.6035x; 1.6035x over previous
//
#include <hip/hip_runtime.h>

// EncodecEuclideanCodebook — R10.
//   x: [131072, 128] fp32, embed: [1024, 128] fp32.
//   out: quantize [131072*128] f32, then embed_ind [131072] (indices as f32).
//
// score = 2*x.e - ||e||^2 (argmax-equivalent). Approx: K=128 fp16 MFMA GEMM
// fp16(x) . fp16(e), MARGIN 0.10 (~22 sigma). Flagged rows (~1%) re-scored
// exactly in fp32 by refine_kernel. Gather fused into vq/refine epilogues.
//
// R9 post-mortem: amdgpu_waves_per_eu(8) CAPPED the allocator at 32 VGPR vs
// ~100 live -> 860MB scratch traffic (FETCH 495MB / WRITE 492MB), vq 256us.
// The 128-row/1024-thr structure itself was fine (occ 80%, absmax 0).
// R10 = R9 minus the attr (launch_bounds(1024) alone -> cap 128, live ~100
// fits, no spill) plus: fold -||e||^2/2 into acc init (argmax(2a-e2) ==
// argmax(a-e2/2)): 4x ds_read_b128/chunk replaces 128 fma + 128 ds_read_b32
// per thread; margin compare at MARGIN/2 in halved units (same flag set).
// Pipeline unchanged from R8b: counted vmcnt (never 0 in loop), depth-2
// prefetch, 3 rotating 16KB e-buffers, fences after raw barriers.

#define N_ROWS (64 * 2048)
#define DIM 128
#define BINS 1024
#define MARGIN 0.10f

typedef __attribute__((ext_vector_type(8))) _Float16 half8;  // 16 B = 4 VGPR
typedef __attribute__((ext_vector_type(4))) float f32x4;

__device__ __forceinline__ void glds16(const void* g, void* l) {
    __builtin_amdgcn_global_load_lds((const __attribute__((address_space(1))) char*)g,
                                     (__attribute__((address_space(3))) char*)l, 16, 0, 0);
}

// e_img: 16 stages x 16 KB fp16. Stage S = chunk*4 + ks holds bins
// [256*chunk,+256) x k [32*ks,+32); byte off = b*64 + 16*(g2 ^ ((b>>2)&3)).
__global__ __launch_bounds__(256) void prep_kernel(const float* __restrict__ embed,
                                                   _Float16* __restrict__ e_img,
                                                   float* __restrict__ esq_g,
                                                   int* __restrict__ counter) {
    int bin = blockIdx.x * 256 + threadIdx.x;
    if (bin == 0) *counter = 0;
    const float4* e4 = (const float4*)(embed + (size_t)bin * DIM);
    int c = bin >> 8, b = bin & 255;
    float s = 0.f;
#pragma unroll
    for (int g = 0; g < 16; ++g) {
        float4 v0 = e4[2 * g], v1 = e4[2 * g + 1];
        s += v0.x * v0.x + v0.y * v0.y + v0.z * v0.z + v0.w * v0.w;
        s += v1.x * v1.x + v1.y * v1.y + v1.z * v1.z + v1.w * v1.w;
        float f[8] = {v0.x, v0.y, v0.z, v0.w, v1.x, v1.y, v1.z, v1.w};
        half8 H;
#pragma unroll
        for (int j = 0; j < 8; ++j) H[j] = (_Float16)f[j];
        int ks = g >> 2, g2 = g & 3;
        size_t off = ((size_t)(c * 4 + ks) << 14) + (size_t)b * 64 + 16 * (g2 ^ ((b >> 2) & 3));
        *(half8*)((char*)e_img + off) = H;
    }
    esq_g[bin] = s;
}

// 1024 threads = 16 waves. Wave wv: row-group h = wv>>2 (32 rows of 128),
// bin-quarter bq = wv&3 (64 bins of each 256-bin chunk). Wave tile 64x32.
// LDS 52 KB: [0,48K) three 16KB e-stage buffers (buf0+buf1 double as xh
// (32KB) during the prologue), [48K,52K) esq (live whole kernel).
__global__ __launch_bounds__(1024)
void vq_mfma_kernel(const float* __restrict__ x,
                    const _Float16* __restrict__ e_img,
                    const float* __restrict__ esq_g,
                    const float* __restrict__ embed,
                    float* __restrict__ out_idx,
                    float* __restrict__ out_q,
                    int* __restrict__ list,
                    int* __restrict__ counter) {
    __shared__ __align__(16) char smem[53248];
    float* esq_s = (float*)(smem + 49152);

    const int t = threadIdx.x;
    const int wv = t >> 6, lane = t & 63, q = lane >> 4, L15 = lane & 15;
    const int h = wv >> 2, bq = wv & 3;
    const int R0 = blockIdx.x * 128;

    // ---- stage esq -> LDS; convert x tile (128 rows) -> fp16 in LDS ----
    {
        esq_s[t] = esq_g[t];
        const float4* xg = (const float4*)(x + (size_t)R0 * DIM);
#pragma unroll
        for (int qq = 0; qq < 2; ++qq) {
            int G = qq * 1024 + t;
            int row = G >> 4, g = G & 15;
            float4 v0 = xg[row * 32 + 2 * g];
            float4 v1 = xg[row * 32 + 2 * g + 1];
            float f[8] = {v0.x, v0.y, v0.z, v0.w, v1.x, v1.y, v1.z, v1.w};
            half8 H;
#pragma unroll
            for (int j = 0; j < 8; ++j) H[j] = (_Float16)f[j];
            int off = row * 256 + 16 * (g ^ (row & 7));
            *(half8*)(smem + off) = H;
        }
    }
    __syncthreads();

    // ---- preload x B-fragments: rows 32h+16nt+L15, k-group (ks<<2)|q ----
    half8 bh[4][2];
    const int rbase = (32 * h + L15) * 256;
#pragma unroll
    for (int ks = 0; ks < 4; ++ks) {
        const int sB = 16 * ((((ks << 2) | q)) ^ (L15 & 7));
#pragma unroll
        for (int nt = 0; nt < 2; ++nt)
            bh[ks][nt] = *(const half8*)(smem + rbase + nt * 4096 + sB);
    }
    __syncthreads();   // xh (buf0+buf1) dead -> e-stage buffers 0,1

    const int aOff = (64 * bq + L15) * 64 + 16 * (q ^ ((L15 >> 2) & 3));

    // ---- prologue prefetch: stages 0,1 -> buf0,buf1 (1 KB per wave each) ----
    {
        const char* src = (const char*)e_img;
        const int off = wv << 10;
#pragma unroll
        for (int st = 0; st < 2; ++st)
            glds16(src + ((size_t)st << 14) + off + lane * 16, smem + st * 16384 + off);
        asm volatile("s_waitcnt vmcnt(1)" ::: "memory");   // stage-0 segment landed
    }
    __builtin_amdgcn_s_barrier();
    asm volatile("" ::: "memory");                         // no reads hoist above barrier

    float best[2], sec[2];
    int bidx[2];
#pragma unroll
    for (int nt = 0; nt < 2; ++nt) { best[nt] = -3.4e38f; sec[nt] = -3.4e38f; bidx[nt] = 0; }

    for (int c = 0; c < 4; ++c) {                 // 4 chunks of 256 bins
        // acc init = -||e||^2/2: argmax(2a - e2) == argmax(a - e2/2).
        f32x4 acc[4][2];
#pragma unroll
        for (int mt = 0; mt < 4; ++mt) {
            f32x4 e2v = *(const f32x4*)&esq_s[256 * c + 64 * bq + 16 * mt + 4 * q];
            f32x4 init;
#pragma unroll
            for (int r = 0; r < 4; ++r) init[r] = -0.5f * e2v[r];
            acc[mt][0] = init;
            acc[mt][1] = init;
        }

#pragma unroll
        for (int s = 0; s < 4; ++s) {             // 4 k-stages of 32
            const int gs = c * 4 + s;
            // issue prefetch of stage gs+2 first: overlaps this stage's MFMAs.
            // dst buf (gs+2)%3 == (gs-1)%3: readers done at entry barrier.
            if (gs < 14) {
                const char* src = (const char*)e_img + ((size_t)(gs + 2) << 14);
                char* dst = smem + ((gs + 2) % 3) * 16384;
                const int off = wv << 10;
                glds16(src + off + lane * 16, dst + off);
            }
            const char* buf = smem + (gs % 3) * 16384;
            half8 a[4];
#pragma unroll
            for (int mt = 0; mt < 4; ++mt)
                a[mt] = *(const half8*)(buf + aOff + mt * 1024);
#pragma unroll
            for (int mt = 0; mt < 4; ++mt)
#pragma unroll
                for (int nt = 0; nt < 2; ++nt)
                    acc[mt][nt] = __builtin_amdgcn_mfma_f32_16x16x32_f16(a[mt], bh[s][nt], acc[mt][nt], 0, 0, 0);
            // counted wait: keep newest stage's load in flight, guarantee
            // stage gs+1's segment (the oldest outstanding) has landed.
            if (gs < 14) {
                asm volatile("s_waitcnt vmcnt(1)" ::: "memory");
            } else if (gs == 14) {
                asm volatile("s_waitcnt vmcnt(0)" ::: "memory");
            }
            __builtin_amdgcn_s_barrier();
            asm volatile("" ::: "memory");        // pin next stage's ds_reads below
        }

        // ---- chunk epilogue: per-lane top-2 over its 16 bins (ascending) ----
        // sc = acc (already holds x.e - e2/2). sec' = med3(sc,best,sec) is the
        // exact new second-max; best/bidx via strict > (keeps first occurrence).
#pragma unroll
        for (int mt = 0; mt < 4; ++mt)
#pragma unroll
            for (int r = 0; r < 4; ++r) {
                int bin = 256 * c + 64 * bq + 16 * mt + 4 * q + r;
#pragma unroll
                for (int nt = 0; nt < 2; ++nt) {
                    float sc = acc[mt][nt][r];
                    bool gt = sc > best[nt];
                    sec[nt] = __builtin_amdgcn_fmed3f(sc, best[nt], sec[nt]);
                    best[nt] = gt ? sc : best[nt];
                    bidx[nt] = gt ? bin : bidx[nt];
                }
            }
    }

    // ---- cross-quad top-2 merge (within wave) ----
#pragma unroll
    for (int nt = 0; nt < 2; ++nt) {
        for (int off = 16; off <= 32; off <<= 1) {
            float ob = __shfl_xor(best[nt], off);
            float os = __shfl_xor(sec[nt], off);
            int oi = __shfl_xor(bidx[nt], off);
            if (ob > best[nt]) { sec[nt] = fmaxf(best[nt], os); best[nt] = ob; bidx[nt] = oi; }
            else sec[nt] = fmaxf(sec[nt], ob);
        }
    }
    __syncthreads();                              // full drain; e-bufs dead -> scratch
    float* sv = (float*)smem;                     // [16 waves][32 rows][b,s,i]
    int* fidx = (int*)(smem + 8192);              // [128]
    if (q == 0) {
#pragma unroll
        for (int nt = 0; nt < 2; ++nt) {
            int base = (wv * 32 + 16 * nt + L15) * 3;
            sv[base] = best[nt]; sv[base + 1] = sec[nt];
            ((int*)sv)[base + 2] = bidx[nt];
        }
    }
    __syncthreads();
    if (t < 128) {
        int hh = t >> 5, r32 = t & 31;
        int base0 = ((4 * hh) * 32 + r32) * 3;
        float b0 = sv[base0], s0 = sv[base0 + 1];
        int i0 = ((int*)sv)[base0 + 2];
        for (int w = 1; w < 4; ++w) {
            int base = ((4 * hh + w) * 32 + r32) * 3;
            float ob = sv[base], os = sv[base + 1];
            int oi = ((int*)sv)[base + 2];
            if (ob > b0) { s0 = fmaxf(b0, os); b0 = ob; i0 = oi; }
            else s0 = fmaxf(s0, ob);
        }
        out_idx[R0 + t] = (float)i0;
        fidx[t] = i0;
        if (b0 - s0 < 0.5f * MARGIN) {            // halved-score units
            int pos = atomicAdd(counter, 1);
            list[pos] = R0 + t;
        }
    }
    __syncthreads();

    // ---- fused gather: 128 rows x 32 float4 = 4 per thread ----
    {
        const float4* eg = (const float4*)embed;
        float4* og = (float4*)(out_q + (size_t)R0 * DIM);
#pragma unroll
        for (int i = 0; i < 4; ++i) {
            int f = i * 1024 + t;
            int r = f >> 5, cc = f & 31;
            og[(size_t)r * 32 + cc] = eg[(size_t)fidx[r] * 32 + cc];
        }
    }
}

// Compacted exact fp32 refine (16 flagged rows x 1024 bins per tile), with
// fused gather for its rows. First-max tie-break = reference semantics.
#define SWB(r, c4) ((r) * 128 + 4 * ((c4) ^ ((r) & 31)))
__global__ __launch_bounds__(256) void refine_kernel(const float* __restrict__ x,
                                                     const float* __restrict__ embed,
                                                     const float* __restrict__ esq_g,
                                                     float* __restrict__ out_idx,
                                                     float* __restrict__ out_q,
                                                     const int* __restrict__ list,
                                                     const int* __restrict__ counter) {
    __shared__ float xr[16 * 128];    // 8 KB
    __shared__ float bs[64 * 128];    // 32 KB
    __shared__ int rowbuf[16];
    __shared__ int ridx[16];

    const int t = threadIdx.x;
    const int tx = t & 63;
    const int ty = t >> 6;
    const int F = *counter;

    for (int tile = blockIdx.x; tile * 16 < F; tile += gridDim.x) {
        const int base = tile * 16;
        __syncthreads();
        if (t < 16) rowbuf[t] = list[min(base + t, F - 1)];
        __syncthreads();
#pragma unroll
        for (int i = 0; i < 2; ++i) {
            int f = i * 256 + t;
            int r = f >> 5, cc = f & 31;
            float4 v = ((const float4*)(x + (size_t)rowbuf[r] * DIM))[cc];
            *(float4*)&xr[r * 128 + cc * 4] = v;
        }

        float bb[4]; int bi[4];
#pragma unroll
        for (int rr = 0; rr < 4; ++rr) { bb[rr] = -3.4e38f; bi[rr] = 0; }

        for (int chunk = 0; chunk < 16; ++chunk) {
            __syncthreads();
            const float4* eg = (const float4*)(embed + (size_t)chunk * 64 * DIM);
#pragma unroll
            for (int i = 0; i < 8; ++i) {
                int f = i * 256 + t;
                int r = f >> 5, cc = f & 31;
                float4 v = eg[f];
                *(float4*)&bs[SWB(r, cc)] = v;
            }
            __syncthreads();

            float acc[4];
#pragma unroll
            for (int rr = 0; rr < 4; ++rr) acc[rr] = 0.f;
#pragma unroll 8
            for (int k4 = 0; k4 < 32; ++k4) {
                float4 b = *(const float4*)&bs[SWB(tx, k4)];
#pragma unroll
                for (int rr = 0; rr < 4; ++rr) {
                    float4 a = *(const float4*)&xr[(4 * ty + rr) * 128 + k4 * 4];
                    acc[rr] = fmaf(a.x, b.x, acc[rr]);
                    acc[rr] = fmaf(a.y, b.y, acc[rr]);
                    acc[rr] = fmaf(a.z, b.z, acc[rr]);
                    acc[rr] = fmaf(a.w, b.w, acc[rr]);
                }
            }
            const int bin = chunk * 64 + tx;
            const float e2 = esq_g[bin];
#pragma unroll
            for (int rr = 0; rr < 4; ++rr) {
                float sc = 2.f * acc[rr] - e2;
                if (sc > bb[rr]) { bb[rr] = sc; bi[rr] = bin; }
            }
        }

        __syncthreads();
        float* vals = bs;
        int* idxs = (int*)(bs + 1024);
#pragma unroll
        for (int rr = 0; rr < 4; ++rr) {
            vals[(4 * ty + rr) * 64 + tx] = bb[rr];
            idxs[(4 * ty + rr) * 64 + tx] = bi[rr];
        }
        __syncthreads();
        if (t < 16) {
            float bv = vals[t * 64];
            int bix = idxs[t * 64];
            for (int j = 1; j < 64; ++j) {
                float v = vals[t * 64 + j];
                int id = idxs[t * 64 + j];
                if (v > bv || (v == bv && id < bix)) { bv = v; bix = id; }
            }
            ridx[t] = bix;
            if (base + t < F) out_idx[rowbuf[t]] = (float)bix;
        }
        __syncthreads();
        // fused gather for this tile's rows (dup tail rows rewrite same data)
        {
            const float4* eg = (const float4*)embed;
#pragma unroll
            for (int i = 0; i < 2; ++i) {
                int f = i * 256 + t;
                int r = f >> 5, cc = f & 31;
                float4* og = (float4*)(out_q + (size_t)rowbuf[r] * DIM);
                og[cc] = eg[(size_t)ridx[r] * 32 + cc];
            }
        }
    }
}

extern "C" void kernel_launch(void* const* d_in, const int* in_sizes, int n_in,
                              void* d_out, int out_size, void* d_ws, size_t ws_size,
                              hipStream_t stream) {
    const float* x = (const float*)d_in[0];
    const float* embed = (const float*)d_in[1];
    float* out_q = (float*)d_out;
    float* out_idx = out_q + (size_t)N_ROWS * DIM;
    char* wsb = (char*)d_ws;
    _Float16* e_img = (_Float16*)wsb;                         // 256 KB (16 x 16 KB)
    float* esq_g = (float*)(wsb + (16 << 14));                // 4 KB
    int* counter = (int*)(wsb + (16 << 14) + 4096);           // 4 B (+pad)
    int* list = (int*)(wsb + (16 << 14) + 4096 + 128);        // 512 KB

    prep_kernel<<<BINS / 256, 256, 0, stream>>>(embed, e_img, esq_g, counter);
    vq_mfma_kernel<<<N_ROWS / 128, 1024, 0, stream>>>(x, e_img, esq_g, embed,
                                                      out_idx, out_q, list, counter);
    refine_kernel<<<1024, 256, 0, stream>>>(x, embed, esq_g, out_idx, out_q, list, counter);
}

// Round 8
// 253.659 us; speedup vs baseline: 1.6501x; 1.0291x over previous
//
#include <hip/hip_runtime.h>

// EncodecEuclideanCodebook — R11.
//   x: [131072, 128] fp32, embed: [1024, 128] fp32.
//   out: quantize [131072*128] f32, then embed_ind [131072] (indices as f32).
//
// score = 2*x.e - ||e||^2 (argmax-equivalent). Approx: K=128 fp16 MFMA GEMM
// fp16(x) . fp16(e), MARGIN 0.10 (~22 sigma). Flagged rows (~1%) re-scored
// exactly in fp32 by refine_kernel. Gather fused into vq/refine epilogues.
//
// R10 post-mortem: bare launch_bounds(1024) -> allocator targeted 8 waves/EU,
// capped 64 VGPR vs ~100 live -> 72MB spill traffic (WRITE 113.5 = 66+47,
// FETCH 62.5 = 37+25), vq 98us. Exact replay of the R4 lesson: min-occupancy
// hints are not a register budget; only amdgpu_waves_per_eu(min,max) pins it
// (R5 precedent: (2,2) -> VGPR=128, no spill).
// R11 = R10 + amdgpu_waves_per_eu(4,4): 16-wave block = 4 waves/EU at
// 1 block/CU -> 128-VGPR budget, ~100 live fits, zero spill. Stage loop is
// then load-throughput-bound (~300cyc/stage L2) under depth-2 prefetch.
// All else byte-identical to R10 (med3 epilogue + acc-init validated).

#define N_ROWS (64 * 2048)
#define DIM 128
#define BINS 1024
#define MARGIN 0.10f

typedef __attribute__((ext_vector_type(8))) _Float16 half8;  // 16 B = 4 VGPR
typedef __attribute__((ext_vector_type(4))) float f32x4;

__device__ __forceinline__ void glds16(const void* g, void* l) {
    __builtin_amdgcn_global_load_lds((const __attribute__((address_space(1))) char*)g,
                                     (__attribute__((address_space(3))) char*)l, 16, 0, 0);
}

// e_img: 16 stages x 16 KB fp16. Stage S = chunk*4 + ks holds bins
// [256*chunk,+256) x k [32*ks,+32); byte off = b*64 + 16*(g2 ^ ((b>>2)&3)).
__global__ __launch_bounds__(256) void prep_kernel(const float* __restrict__ embed,
                                                   _Float16* __restrict__ e_img,
                                                   float* __restrict__ esq_g,
                                                   int* __restrict__ counter) {
    int bin = blockIdx.x * 256 + threadIdx.x;
    if (bin == 0) *counter = 0;
    const float4* e4 = (const float4*)(embed + (size_t)bin * DIM);
    int c = bin >> 8, b = bin & 255;
    float s = 0.f;
#pragma unroll
    for (int g = 0; g < 16; ++g) {
        float4 v0 = e4[2 * g], v1 = e4[2 * g + 1];
        s += v0.x * v0.x + v0.y * v0.y + v0.z * v0.z + v0.w * v0.w;
        s += v1.x * v1.x + v1.y * v1.y + v1.z * v1.z + v1.w * v1.w;
        float f[8] = {v0.x, v0.y, v0.z, v0.w, v1.x, v1.y, v1.z, v1.w};
        half8 H;
#pragma unroll
        for (int j = 0; j < 8; ++j) H[j] = (_Float16)f[j];
        int ks = g >> 2, g2 = g & 3;
        size_t off = ((size_t)(c * 4 + ks) << 14) + (size_t)b * 64 + 16 * (g2 ^ ((b >> 2) & 3));
        *(half8*)((char*)e_img + off) = H;
    }
    esq_g[bin] = s;
}

// 1024 threads = 16 waves. Wave wv: row-group h = wv>>2 (32 rows of 128),
// bin-quarter bq = wv&3 (64 bins of each 256-bin chunk). Wave tile 64x32.
// LDS 52 KB: [0,48K) three 16KB e-stage buffers (buf0+buf1 double as xh
// (32KB) during the prologue), [48K,52K) esq (live whole kernel).
__global__ __launch_bounds__(1024) __attribute__((amdgpu_waves_per_eu(4, 4)))
void vq_mfma_kernel(const float* __restrict__ x,
                    const _Float16* __restrict__ e_img,
                    const float* __restrict__ esq_g,
                    const float* __restrict__ embed,
                    float* __restrict__ out_idx,
                    float* __restrict__ out_q,
                    int* __restrict__ list,
                    int* __restrict__ counter) {
    __shared__ __align__(16) char smem[53248];
    float* esq_s = (float*)(smem + 49152);

    const int t = threadIdx.x;
    const int wv = t >> 6, lane = t & 63, q = lane >> 4, L15 = lane & 15;
    const int h = wv >> 2, bq = wv & 3;
    const int R0 = blockIdx.x * 128;

    // ---- stage esq -> LDS; convert x tile (128 rows) -> fp16 in LDS ----
    {
        esq_s[t] = esq_g[t];
        const float4* xg = (const float4*)(x + (size_t)R0 * DIM);
#pragma unroll
        for (int qq = 0; qq < 2; ++qq) {
            int G = qq * 1024 + t;
            int row = G >> 4, g = G & 15;
            float4 v0 = xg[row * 32 + 2 * g];
            float4 v1 = xg[row * 32 + 2 * g + 1];
            float f[8] = {v0.x, v0.y, v0.z, v0.w, v1.x, v1.y, v1.z, v1.w};
            half8 H;
#pragma unroll
            for (int j = 0; j < 8; ++j) H[j] = (_Float16)f[j];
            int off = row * 256 + 16 * (g ^ (row & 7));
            *(half8*)(smem + off) = H;
        }
    }
    __syncthreads();

    // ---- preload x B-fragments: rows 32h+16nt+L15, k-group (ks<<2)|q ----
    half8 bh[4][2];
    const int rbase = (32 * h + L15) * 256;
#pragma unroll
    for (int ks = 0; ks < 4; ++ks) {
        const int sB = 16 * ((((ks << 2) | q)) ^ (L15 & 7));
#pragma unroll
        for (int nt = 0; nt < 2; ++nt)
            bh[ks][nt] = *(const half8*)(smem + rbase + nt * 4096 + sB);
    }
    __syncthreads();   // xh (buf0+buf1) dead -> e-stage buffers 0,1

    const int aOff = (64 * bq + L15) * 64 + 16 * (q ^ ((L15 >> 2) & 3));

    // ---- prologue prefetch: stages 0,1 -> buf0,buf1 (1 KB per wave each) ----
    {
        const char* src = (const char*)e_img;
        const int off = wv << 10;
#pragma unroll
        for (int st = 0; st < 2; ++st)
            glds16(src + ((size_t)st << 14) + off + lane * 16, smem + st * 16384 + off);
        asm volatile("s_waitcnt vmcnt(1)" ::: "memory");   // stage-0 segment landed
    }
    __builtin_amdgcn_s_barrier();
    asm volatile("" ::: "memory");                         // no reads hoist above barrier

    float best[2], sec[2];
    int bidx[2];
#pragma unroll
    for (int nt = 0; nt < 2; ++nt) { best[nt] = -3.4e38f; sec[nt] = -3.4e38f; bidx[nt] = 0; }

    for (int c = 0; c < 4; ++c) {                 // 4 chunks of 256 bins
        // acc init = -||e||^2/2: argmax(2a - e2) == argmax(a - e2/2).
        f32x4 acc[4][2];
#pragma unroll
        for (int mt = 0; mt < 4; ++mt) {
            f32x4 e2v = *(const f32x4*)&esq_s[256 * c + 64 * bq + 16 * mt + 4 * q];
            f32x4 init;
#pragma unroll
            for (int r = 0; r < 4; ++r) init[r] = -0.5f * e2v[r];
            acc[mt][0] = init;
            acc[mt][1] = init;
        }

#pragma unroll
        for (int s = 0; s < 4; ++s) {             // 4 k-stages of 32
            const int gs = c * 4 + s;
            // issue prefetch of stage gs+2 first: overlaps this stage's MFMAs.
            // dst buf (gs+2)%3 == (gs-1)%3: readers done at entry barrier.
            if (gs < 14) {
                const char* src = (const char*)e_img + ((size_t)(gs + 2) << 14);
                char* dst = smem + ((gs + 2) % 3) * 16384;
                const int off = wv << 10;
                glds16(src + off + lane * 16, dst + off);
            }
            const char* buf = smem + (gs % 3) * 16384;
            half8 a[4];
#pragma unroll
            for (int mt = 0; mt < 4; ++mt)
                a[mt] = *(const half8*)(buf + aOff + mt * 1024);
#pragma unroll
            for (int mt = 0; mt < 4; ++mt)
#pragma unroll
                for (int nt = 0; nt < 2; ++nt)
                    acc[mt][nt] = __builtin_amdgcn_mfma_f32_16x16x32_f16(a[mt], bh[s][nt], acc[mt][nt], 0, 0, 0);
            // counted wait: keep newest stage's load in flight, guarantee
            // stage gs+1's segment (the oldest outstanding) has landed.
            if (gs < 14) {
                asm volatile("s_waitcnt vmcnt(1)" ::: "memory");
            } else if (gs == 14) {
                asm volatile("s_waitcnt vmcnt(0)" ::: "memory");
            }
            __builtin_amdgcn_s_barrier();
            asm volatile("" ::: "memory");        // pin next stage's ds_reads below
        }

        // ---- chunk epilogue: per-lane top-2 over its 16 bins (ascending) ----
        // sc = acc (already holds x.e - e2/2). sec' = med3(sc,best,sec) is the
        // exact new second-max; best/bidx via strict > (keeps first occurrence).
#pragma unroll
        for (int mt = 0; mt < 4; ++mt)
#pragma unroll
            for (int r = 0; r < 4; ++r) {
                int bin = 256 * c + 64 * bq + 16 * mt + 4 * q + r;
#pragma unroll
                for (int nt = 0; nt < 2; ++nt) {
                    float sc = acc[mt][nt][r];
                    bool gt = sc > best[nt];
                    sec[nt] = __builtin_amdgcn_fmed3f(sc, best[nt], sec[nt]);
                    best[nt] = gt ? sc : best[nt];
                    bidx[nt] = gt ? bin : bidx[nt];
                }
            }
    }

    // ---- cross-quad top-2 merge (within wave) ----
#pragma unroll
    for (int nt = 0; nt < 2; ++nt) {
        for (int off = 16; off <= 32; off <<= 1) {
            float ob = __shfl_xor(best[nt], off);
            float os = __shfl_xor(sec[nt], off);
            int oi = __shfl_xor(bidx[nt], off);
            if (ob > best[nt]) { sec[nt] = fmaxf(best[nt], os); best[nt] = ob; bidx[nt] = oi; }
            else sec[nt] = fmaxf(sec[nt], ob);
        }
    }
    __syncthreads();                              // full drain; e-bufs dead -> scratch
    float* sv = (float*)smem;                     // [16 waves][32 rows][b,s,i]
    int* fidx = (int*)(smem + 8192);              // [128]
    if (q == 0) {
#pragma unroll
        for (int nt = 0; nt < 2; ++nt) {
            int base = (wv * 32 + 16 * nt + L15) * 3;
            sv[base] = best[nt]; sv[base + 1] = sec[nt];
            ((int*)sv)[base + 2] = bidx[nt];
        }
    }
    __syncthreads();
    if (t < 128) {
        int hh = t >> 5, r32 = t & 31;
        int base0 = ((4 * hh) * 32 + r32) * 3;
        float b0 = sv[base0], s0 = sv[base0 + 1];
        int i0 = ((int*)sv)[base0 + 2];
        for (int w = 1; w < 4; ++w) {
            int base = ((4 * hh + w) * 32 + r32) * 3;
            float ob = sv[base], os = sv[base + 1];
            int oi = ((int*)sv)[base + 2];
            if (ob > b0) { s0 = fmaxf(b0, os); b0 = ob; i0 = oi; }
            else s0 = fmaxf(s0, ob);
        }
        out_idx[R0 + t] = (float)i0;
        fidx[t] = i0;
        if (b0 - s0 < 0.5f * MARGIN) {            // halved-score units
            int pos = atomicAdd(counter, 1);
            list[pos] = R0 + t;
        }
    }
    __syncthreads();

    // ---- fused gather: 128 rows x 32 float4 = 4 per thread ----
    {
        const float4* eg = (const float4*)embed;
        float4* og = (float4*)(out_q + (size_t)R0 * DIM);
#pragma unroll
        for (int i = 0; i < 4; ++i) {
            int f = i * 1024 + t;
            int r = f >> 5, cc = f & 31;
            og[(size_t)r * 32 + cc] = eg[(size_t)fidx[r] * 32 + cc];
        }
    }
}

// Compacted exact fp32 refine (16 flagged rows x 1024 bins per tile), with
// fused gather for its rows. First-max tie-break = reference semantics.
#define SWB(r, c4) ((r) * 128 + 4 * ((c4) ^ ((r) & 31)))
__global__ __launch_bounds__(256) void refine_kernel(const float* __restrict__ x,
                                                     const float* __restrict__ embed,
                                                     const float* __restrict__ esq_g,
                                                     float* __restrict__ out_idx,
                                                     float* __restrict__ out_q,
                                                     const int* __restrict__ list,
                                                     const int* __restrict__ counter) {
    __shared__ float xr[16 * 128];    // 8 KB
    __shared__ float bs[64 * 128];    // 32 KB
    __shared__ int rowbuf[16];
    __shared__ int ridx[16];

    const int t = threadIdx.x;
    const int tx = t & 63;
    const int ty = t >> 6;
    const int F = *counter;

    for (int tile = blockIdx.x; tile * 16 < F; tile += gridDim.x) {
        const int base = tile * 16;
        __syncthreads();
        if (t < 16) rowbuf[t] = list[min(base + t, F - 1)];
        __syncthreads();
#pragma unroll
        for (int i = 0; i < 2; ++i) {
            int f = i * 256 + t;
            int r = f >> 5, cc = f & 31;
            float4 v = ((const float4*)(x + (size_t)rowbuf[r] * DIM))[cc];
            *(float4*)&xr[r * 128 + cc * 4] = v;
        }

        float bb[4]; int bi[4];
#pragma unroll
        for (int rr = 0; rr < 4; ++rr) { bb[rr] = -3.4e38f; bi[rr] = 0; }

        for (int chunk = 0; chunk < 16; ++chunk) {
            __syncthreads();
            const float4* eg = (const float4*)(embed + (size_t)chunk * 64 * DIM);
#pragma unroll
            for (int i = 0; i < 8; ++i) {
                int f = i * 256 + t;
                int r = f >> 5, cc = f & 31;
                float4 v = eg[f];
                *(float4*)&bs[SWB(r, cc)] = v;
            }
            __syncthreads();

            float acc[4];
#pragma unroll
            for (int rr = 0; rr < 4; ++rr) acc[rr] = 0.f;
#pragma unroll 8
            for (int k4 = 0; k4 < 32; ++k4) {
                float4 b = *(const float4*)&bs[SWB(tx, k4)];
#pragma unroll
                for (int rr = 0; rr < 4; ++rr) {
                    float4 a = *(const float4*)&xr[(4 * ty + rr) * 128 + k4 * 4];
                    acc[rr] = fmaf(a.x, b.x, acc[rr]);
                    acc[rr] = fmaf(a.y, b.y, acc[rr]);
                    acc[rr] = fmaf(a.z, b.z, acc[rr]);
                    acc[rr] = fmaf(a.w, b.w, acc[rr]);
                }
            }
            const int bin = chunk * 64 + tx;
            const float e2 = esq_g[bin];
#pragma unroll
            for (int rr = 0; rr < 4; ++rr) {
                float sc = 2.f * acc[rr] - e2;
                if (sc > bb[rr]) { bb[rr] = sc; bi[rr] = bin; }
            }
        }

        __syncthreads();
        float* vals = bs;
        int* idxs = (int*)(bs + 1024);
#pragma unroll
        for (int rr = 0; rr < 4; ++rr) {
            vals[(4 * ty + rr) * 64 + tx] = bb[rr];
            idxs[(4 * ty + rr) * 64 + tx] = bi[rr];
        }
        __syncthreads();
        if (t < 16) {
            float bv = vals[t * 64];
            int bix = idxs[t * 64];
            for (int j = 1; j < 64; ++j) {
                float v = vals[t * 64 + j];
                int id = idxs[t * 64 + j];
                if (v > bv || (v == bv && id < bix)) { bv = v; bix = id; }
            }
            ridx[t] = bix;
            if (base + t < F) out_idx[rowbuf[t]] = (float)bix;
        }
        __syncthreads();
        // fused gather for this tile's rows (dup tail rows rewrite same data)
        {
            const float4* eg = (const float4*)embed;
#pragma unroll
            for (int i = 0; i < 2; ++i) {
                int f = i * 256 + t;
                int r = f >> 5, cc = f & 31;
                float4* og = (float4*)(out_q + (size_t)rowbuf[r] * DIM);
                og[cc] = eg[(size_t)ridx[r] * 32 + cc];
            }
        }
    }
}

extern "C" void kernel_launch(void* const* d_in, const int* in_sizes, int n_in,
                              void* d_out, int out_size, void* d_ws, size_t ws_size,
                              hipStream_t stream) {
    const float* x = (const float*)d_in[0];
    const float* embed = (const float*)d_in[1];
    float* out_q = (float*)d_out;
    float* out_idx = out_q + (size_t)N_ROWS * DIM;
    char* wsb = (char*)d_ws;
    _Float16* e_img = (_Float16*)wsb;                         // 256 KB (16 x 16 KB)
    float* esq_g = (float*)(wsb + (16 << 14));                // 4 KB
    int* counter = (int*)(wsb + (16 << 14) + 4096);           // 4 B (+pad)
    int* list = (int*)(wsb + (16 << 14) + 4096 + 128);        // 512 KB

    prep_kernel<<<BINS / 256, 256, 0, stream>>>(embed, e_img, esq_g, counter);
    vq_mfma_kernel<<<N_ROWS / 128, 1024, 0, stream>>>(x, e_img, esq_g, embed,
                                                      out_idx, out_q, list, counter);
    refine_kernel<<<1024, 256, 0, stream>>>(x, embed, esq_g, out_idx, out_q, list, counter);
}

// Round 9
// 237.616 us; speedup vs baseline: 1.7615x; 1.0675x over previous
//
#include <hip/hip_runtime.h>

// EncodecEuclideanCodebook — R12.
//   x: [131072, 128] fp32, embed: [1024, 128] fp32.
//   out: quantize [131072*128] f32, then embed_ind [131072] (indices as f32).
//
// score = 2*x.e - ||e||^2 (argmax-equivalent). Approx: K=128 fp16 MFMA GEMM
// fp16(x) . fp16(e), MARGIN 0.10 (~22 sigma). Flagged rows (~1%) re-scored
// exactly in fp32 by refine_kernel. Gather fused into vq/refine epilogues.
//
// R11 post-mortem: waves_per_eu(4,4) did NOT deliver 128 VGPR (still 64,
// ~50MB residual spill), vq 90us == R8b's 89. Nothing saturated (MFMA 15 /
// VALU 29 / HBM 22 / Occ 39) -> still convoy-bound: 16 all-wave barriers
// around a shared LDS e-stage. R12 removes the barriers' reason to exist:
//   prep emits e_img in LANE-FRAGMENT order (stage*16K + bq*4K + mt*1K +
//   lane*16), so each wave loads its 4KB/stage E-fragment straight from
//   global (L2-resident, perfectly coalesced dwordx4) into VGPRs. No glds16,
//   no stage buffers, no vmcnt asm, ZERO barriers in the K-loop (4 total).
//   LDS 20KB (x 16K + esq 4K). Geometry = validated R8b 64-row/512-thr;
//   epilogue = validated R10 acc-init + med3 (margin in halved units).

#define N_ROWS (64 * 2048)
#define DIM 128
#define BINS 1024
#define MARGIN 0.10f

typedef __attribute__((ext_vector_type(8))) _Float16 half8;  // 16 B = 4 VGPR
typedef __attribute__((ext_vector_type(4))) float f32x4;

// e_img: 16 stages x 16 KB. Stage gs = c*4 + s holds bins [256c,+256) x
// k [32s,+32), laid out as [bq][mt][lane]: lane (q,L15) owns bin
// 64bq+16mt+L15, k-quad q (8 fp16). Wave (bq) stage-fragment = 4KB contig.
__global__ __launch_bounds__(256) void prep_kernel(const float* __restrict__ embed,
                                                   _Float16* __restrict__ e_img,
                                                   float* __restrict__ esq_g,
                                                   int* __restrict__ counter) {
    int bin = blockIdx.x * 256 + threadIdx.x;
    if (bin == 0) *counter = 0;
    const float4* e4 = (const float4*)(embed + (size_t)bin * DIM);
    int c = bin >> 8, b = bin & 255;
    int bq = b >> 6, mt = (b >> 4) & 3, L15 = b & 15;
    float s = 0.f;
#pragma unroll
    for (int g = 0; g < 16; ++g) {
        float4 v0 = e4[2 * g], v1 = e4[2 * g + 1];
        s += v0.x * v0.x + v0.y * v0.y + v0.z * v0.z + v0.w * v0.w;
        s += v1.x * v1.x + v1.y * v1.y + v1.z * v1.z + v1.w * v1.w;
        float f[8] = {v0.x, v0.y, v0.z, v0.w, v1.x, v1.y, v1.z, v1.w};
        half8 H;
#pragma unroll
        for (int j = 0; j < 8; ++j) H[j] = (_Float16)f[j];
        int gs = c * 4 + (g >> 2), q = g & 3;
        size_t off = ((size_t)(((gs * 4 + bq) * 4) + mt) << 10) + (size_t)((q * 16 + L15) << 4);
        *(half8*)((char*)e_img + off) = H;
    }
    esq_g[bin] = s;
}

// 512 threads = 8 waves. Wave wv: row-half h = wv>>2 (32 rows of 64),
// bin-quarter bq = wv&3 (64 bins of each 256-bin chunk). Wave tile 64x32.
// LDS 20 KB: [0,16K) xh fp16 (live until bh preload; [0,4K) reused as merge
// scratch after sync), [16K,20K) esq (live whole kernel).
__global__ __launch_bounds__(512)
void vq_mfma_kernel(const float* __restrict__ x,
                    const _Float16* __restrict__ e_img,
                    const float* __restrict__ esq_g,
                    const float* __restrict__ embed,
                    float* __restrict__ out_idx,
                    float* __restrict__ out_q,
                    int* __restrict__ list,
                    int* __restrict__ counter) {
    __shared__ __align__(16) char smem[20480];
    float* esq_s = (float*)(smem + 16384);

    const int t = threadIdx.x;
    const int wv = t >> 6, lane = t & 63, q = lane >> 4, L15 = lane & 15;
    const int h = wv >> 2, bq = wv & 3;
    const int R0 = blockIdx.x * 64;

    // ---- stage esq -> LDS; convert x tile (64 rows) -> fp16 in LDS ----
    {
        esq_s[t] = esq_g[t];
        esq_s[t + 512] = esq_g[t + 512];
        const float4* xg = (const float4*)(x + (size_t)R0 * DIM);
#pragma unroll
        for (int qq = 0; qq < 2; ++qq) {
            int G = qq * 512 + t;
            int row = G >> 4, g = G & 15;
            float4 v0 = xg[row * 32 + 2 * g];
            float4 v1 = xg[row * 32 + 2 * g + 1];
            float f[8] = {v0.x, v0.y, v0.z, v0.w, v1.x, v1.y, v1.z, v1.w};
            half8 H;
#pragma unroll
            for (int j = 0; j < 8; ++j) H[j] = (_Float16)f[j];
            int off = row * 256 + 16 * (g ^ (row & 7));
            *(half8*)(smem + off) = H;
        }
    }
    __syncthreads();

    // ---- preload x B-fragments: rows 32h+16nt+L15, k-group (ks<<2)|q ----
    half8 bh[4][2];
    const int rbase = (32 * h + L15) * 256;
#pragma unroll
    for (int ks = 0; ks < 4; ++ks) {
        const int sB = 16 * ((((ks << 2) | q)) ^ (L15 & 7));
#pragma unroll
        for (int nt = 0; nt < 2; ++nt)
            bh[ks][nt] = *(const half8*)(smem + rbase + nt * 4096 + sB);
    }
    // no barrier: xh region is only reused after the post-loop __syncthreads.

    // per-wave E base: + gs*16K advances stages; + mt*1K tiles; + lane*16.
    const char* ebase = (const char*)e_img + (bq << 12) + (lane << 4);

    float best[2], sec[2];
    int bidx[2];
#pragma unroll
    for (int nt = 0; nt < 2; ++nt) { best[nt] = -3.4e38f; sec[nt] = -3.4e38f; bidx[nt] = 0; }

    for (int c = 0; c < 4; ++c) {                 // 4 chunks of 256 bins
        // acc init = -||e||^2/2: argmax(2a - e2) == argmax(a - e2/2).
        f32x4 acc[4][2];
#pragma unroll
        for (int mt = 0; mt < 4; ++mt) {
            f32x4 e2v = *(const f32x4*)&esq_s[256 * c + 64 * bq + 16 * mt + 4 * q];
            f32x4 init;
#pragma unroll
            for (int r = 0; r < 4; ++r) init[r] = -0.5f * e2v[r];
            acc[mt][0] = init;
            acc[mt][1] = init;
        }

#pragma unroll
        for (int s = 0; s < 4; ++s) {             // 4 k-stages of 32
            const char* sb = ebase + (((size_t)(c * 4 + s)) << 14);
            half8 a[4];
#pragma unroll
            for (int mt = 0; mt < 4; ++mt)
                a[mt] = *(const half8*)(sb + mt * 1024);   // coalesced, L2-hit
#pragma unroll
            for (int mt = 0; mt < 4; ++mt)
#pragma unroll
                for (int nt = 0; nt < 2; ++nt)
                    acc[mt][nt] = __builtin_amdgcn_mfma_f32_16x16x32_f16(a[mt], bh[s][nt], acc[mt][nt], 0, 0, 0);
        }

        // ---- chunk epilogue: per-lane top-2 over its 16 bins (ascending) ----
        // sc = acc (already holds x.e - e2/2). sec' = med3(sc,best,sec) is the
        // exact new second-max; best/bidx via strict > (keeps first occurrence).
#pragma unroll
        for (int mt = 0; mt < 4; ++mt)
#pragma unroll
            for (int r = 0; r < 4; ++r) {
                int bin = 256 * c + 64 * bq + 16 * mt + 4 * q + r;
#pragma unroll
                for (int nt = 0; nt < 2; ++nt) {
                    float sc = acc[mt][nt][r];
                    bool gt = sc > best[nt];
                    sec[nt] = __builtin_amdgcn_fmed3f(sc, best[nt], sec[nt]);
                    best[nt] = gt ? sc : best[nt];
                    bidx[nt] = gt ? bin : bidx[nt];
                }
            }
    }

    // ---- cross-quad top-2 merge (within wave) ----
#pragma unroll
    for (int nt = 0; nt < 2; ++nt) {
        for (int off = 16; off <= 32; off <<= 1) {
            float ob = __shfl_xor(best[nt], off);
            float os = __shfl_xor(sec[nt], off);
            int oi = __shfl_xor(bidx[nt], off);
            if (ob > best[nt]) { sec[nt] = fmaxf(best[nt], os); best[nt] = ob; bidx[nt] = oi; }
            else sec[nt] = fmaxf(sec[nt], ob);
        }
    }
    __syncthreads();                              // all bh reads done -> xh reusable
    float* sv = (float*)smem;                     // [8 waves][32 rows][b,s,i]
    int* fidx = (int*)(smem + 4096);              // [64]
    if (q == 0) {
#pragma unroll
        for (int nt = 0; nt < 2; ++nt) {
            int base = (wv * 32 + 16 * nt + L15) * 3;
            sv[base] = best[nt]; sv[base + 1] = sec[nt];
            ((int*)sv)[base + 2] = bidx[nt];
        }
    }
    __syncthreads();
    if (t < 64) {
        int hh = t >> 5, r32 = t & 31;
        int base0 = ((4 * hh) * 32 + r32) * 3;
        float b0 = sv[base0], s0 = sv[base0 + 1];
        int i0 = ((int*)sv)[base0 + 2];
        for (int w = 1; w < 4; ++w) {
            int base = ((4 * hh + w) * 32 + r32) * 3;
            float ob = sv[base], os = sv[base + 1];
            int oi = ((int*)sv)[base + 2];
            if (ob > b0) { s0 = fmaxf(b0, os); b0 = ob; i0 = oi; }
            else s0 = fmaxf(s0, ob);
        }
        out_idx[R0 + t] = (float)i0;
        fidx[t] = i0;
        if (b0 - s0 < 0.5f * MARGIN) {            // halved-score units
            int pos = atomicAdd(counter, 1);
            list[pos] = R0 + t;
        }
    }
    __syncthreads();

    // ---- fused gather: 64 rows x 32 float4 = 4 per thread ----
    {
        const float4* eg = (const float4*)embed;
        float4* og = (float4*)(out_q + (size_t)R0 * DIM);
#pragma unroll
        for (int i = 0; i < 4; ++i) {
            int f = i * 512 + t;
            int r = f >> 5, cc = f & 31;
            og[(size_t)r * 32 + cc] = eg[(size_t)fidx[r] * 32 + cc];
        }
    }
}

// Compacted exact fp32 refine (16 flagged rows x 1024 bins per tile), with
// fused gather for its rows. First-max tie-break = reference semantics.
#define SWB(r, c4) ((r) * 128 + 4 * ((c4) ^ ((r) & 31)))
__global__ __launch_bounds__(256) void refine_kernel(const float* __restrict__ x,
                                                     const float* __restrict__ embed,
                                                     const float* __restrict__ esq_g,
                                                     float* __restrict__ out_idx,
                                                     float* __restrict__ out_q,
                                                     const int* __restrict__ list,
                                                     const int* __restrict__ counter) {
    __shared__ float xr[16 * 128];    // 8 KB
    __shared__ float bs[64 * 128];    // 32 KB
    __shared__ int rowbuf[16];
    __shared__ int ridx[16];

    const int t = threadIdx.x;
    const int tx = t & 63;
    const int ty = t >> 6;
    const int F = *counter;

    for (int tile = blockIdx.x; tile * 16 < F; tile += gridDim.x) {
        const int base = tile * 16;
        __syncthreads();
        if (t < 16) rowbuf[t] = list[min(base + t, F - 1)];
        __syncthreads();
#pragma unroll
        for (int i = 0; i < 2; ++i) {
            int f = i * 256 + t;
            int r = f >> 5, cc = f & 31;
            float4 v = ((const float4*)(x + (size_t)rowbuf[r] * DIM))[cc];
            *(float4*)&xr[r * 128 + cc * 4] = v;
        }

        float bb[4]; int bi[4];
#pragma unroll
        for (int rr = 0; rr < 4; ++rr) { bb[rr] = -3.4e38f; bi[rr] = 0; }

        for (int chunk = 0; chunk < 16; ++chunk) {
            __syncthreads();
            const float4* eg = (const float4*)(embed + (size_t)chunk * 64 * DIM);
#pragma unroll
            for (int i = 0; i < 8; ++i) {
                int f = i * 256 + t;
                int r = f >> 5, cc = f & 31;
                float4 v = eg[f];
                *(float4*)&bs[SWB(r, cc)] = v;
            }
            __syncthreads();

            float acc[4];
#pragma unroll
            for (int rr = 0; rr < 4; ++rr) acc[rr] = 0.f;
#pragma unroll 8
            for (int k4 = 0; k4 < 32; ++k4) {
                float4 b = *(const float4*)&bs[SWB(tx, k4)];
#pragma unroll
                for (int rr = 0; rr < 4; ++rr) {
                    float4 a = *(const float4*)&xr[(4 * ty + rr) * 128 + k4 * 4];
                    acc[rr] = fmaf(a.x, b.x, acc[rr]);
                    acc[rr] = fmaf(a.y, b.y, acc[rr]);
                    acc[rr] = fmaf(a.z, b.z, acc[rr]);
                    acc[rr] = fmaf(a.w, b.w, acc[rr]);
                }
            }
            const int bin = chunk * 64 + tx;
            const float e2 = esq_g[bin];
#pragma unroll
            for (int rr = 0; rr < 4; ++rr) {
                float sc = 2.f * acc[rr] - e2;
                if (sc > bb[rr]) { bb[rr] = sc; bi[rr] = bin; }
            }
        }

        __syncthreads();
        float* vals = bs;
        int* idxs = (int*)(bs + 1024);
#pragma unroll
        for (int rr = 0; rr < 4; ++rr) {
            vals[(4 * ty + rr) * 64 + tx] = bb[rr];
            idxs[(4 * ty + rr) * 64 + tx] = bi[rr];
        }
        __syncthreads();
        if (t < 16) {
            float bv = vals[t * 64];
            int bix = idxs[t * 64];
            for (int j = 1; j < 64; ++j) {
                float v = vals[t * 64 + j];
                int id = idxs[t * 64 + j];
                if (v > bv || (v == bv && id < bix)) { bv = v; bix = id; }
            }
            ridx[t] = bix;
            if (base + t < F) out_idx[rowbuf[t]] = (float)bix;
        }
        __syncthreads();
        // fused gather for this tile's rows (dup tail rows rewrite same data)
        {
            const float4* eg = (const float4*)embed;
#pragma unroll
            for (int i = 0; i < 2; ++i) {
                int f = i * 256 + t;
                int r = f >> 5, cc = f & 31;
                float4* og = (float4*)(out_q + (size_t)rowbuf[r] * DIM);
                og[cc] = eg[(size_t)ridx[r] * 32 + cc];
            }
        }
    }
}

extern "C" void kernel_launch(void* const* d_in, const int* in_sizes, int n_in,
                              void* d_out, int out_size, void* d_ws, size_t ws_size,
                              hipStream_t stream) {
    const float* x = (const float*)d_in[0];
    const float* embed = (const float*)d_in[1];
    float* out_q = (float*)d_out;
    float* out_idx = out_q + (size_t)N_ROWS * DIM;
    char* wsb = (char*)d_ws;
    _Float16* e_img = (_Float16*)wsb;                         // 256 KB (16 x 16 KB)
    float* esq_g = (float*)(wsb + (16 << 14));                // 4 KB
    int* counter = (int*)(wsb + (16 << 14) + 4096);           // 4 B (+pad)
    int* list = (int*)(wsb + (16 << 14) + 4096 + 128);        // 512 KB

    prep_kernel<<<BINS / 256, 256, 0, stream>>>(embed, e_img, esq_g, counter);
    vq_mfma_kernel<<<N_ROWS / 64, 512, 0, stream>>>(x, e_img, esq_g, embed,
                                                    out_idx, out_q, list, counter);
    refine_kernel<<<1024, 256, 0, stream>>>(x, embed, esq_g, out_idx, out_q, list, counter);
}